// Round 1
// baseline (1132.934 us; speedup 1.0000x reference)
//
#include <hip/hip_runtime.h>
#include <hip/hip_bf16.h>
#include <math.h>

#define NN 50000
#define NG 128
#define INC 128
#define HIDC 256
#define NCLS 10

// ---------------- degree / normalization ----------------
__global__ void count_deg(const int* __restrict__ col, int* __restrict__ deg, int E) {
  int stride = gridDim.x * blockDim.x;
  for (int e = blockIdx.x * blockDim.x + threadIdx.x; e < E; e += stride)
    atomicAdd(&deg[col[e]], 1);
}

__global__ void compute_dis(const int* __restrict__ deg, float* __restrict__ dis, int n) {
  int i = blockIdx.x * blockDim.x + threadIdx.x;
  if (i < n) dis[i] = rsqrtf((float)deg[i] + 1.0f);
}

// ---------------- exclusive scan (single block) ----------------
#define SCAN_B 1024
__global__ void scan_offsets(const int* __restrict__ deg, int* __restrict__ offsets, int n) {
  __shared__ int sm[SCAN_B];
  __shared__ int carry_s;
  int tid = threadIdx.x;
  if (tid == 0) carry_s = 0;
  __syncthreads();
  for (int base = 0; base < n; base += SCAN_B) {
    int idx = base + tid;
    int v = (idx < n) ? deg[idx] : 0;
    sm[tid] = v;
    __syncthreads();
    #pragma unroll
    for (int off = 1; off < SCAN_B; off <<= 1) {
      int t = (tid >= off) ? sm[tid - off] : 0;
      __syncthreads();
      sm[tid] += t;
      __syncthreads();
    }
    int incl = sm[tid] + carry_s;
    if (idx < n) offsets[idx + 1] = incl;
    __syncthreads();
    if (tid == SCAN_B - 1) carry_s = incl;
    __syncthreads();
  }
  if (tid == 0) offsets[0] = 0;
}

__global__ void fill_csr(const int* __restrict__ row, const int* __restrict__ col,
                         int* __restrict__ cursor, int* __restrict__ rows_csr, int E) {
  int stride = gridDim.x * blockDim.x;
  for (int e = blockIdx.x * blockDim.x + threadIdx.x; e < E; e += stride) {
    int pos = atomicAdd(&cursor[col[e]], 1);
    rows_csr[pos] = row[e];
  }
}

// ---------------- aggregation: out[i] = sum_{e: col=i} x[row_e]*dis[row]*dis[i] + x[i]*dis[i]^2
template <int C>
__global__ void aggregate(const float* __restrict__ x, const float* __restrict__ dis,
                          const int* __restrict__ offsets, const int* __restrict__ rows_csr,
                          float* __restrict__ out) {
  int i = blockIdx.x;
  int c = threadIdx.x;
  float di = dis[i];
  float acc = x[(long)i * C + c] * di * di;
  int e0 = offsets[i], e1 = offsets[i + 1];
  int e = e0;
  for (; e + 1 < e1; e += 2) {
    int r0 = rows_csr[e];
    int r1 = rows_csr[e + 1];
    float s0 = dis[r0] * di;
    float s1 = dis[r1] * di;
    float v0 = x[(long)r0 * C + c];
    float v1 = x[(long)r1 * C + c];
    acc = fmaf(v0, s0, acc);
    acc = fmaf(v1, s1, acc);
  }
  if (e < e1) {
    int r0 = rows_csr[e];
    acc = fmaf(x[(long)r0 * C + c], dis[r0] * di, acc);
  }
  out[(long)i * C + c] = acc;
}

// ---------------- fused GEMM + bias + relu: Cout = relu(A[M,K] @ W[K,N] + b) ----------------
template <int K>
__global__ __launch_bounds__(256) void gemm_bias_relu(
    const float* __restrict__ A, const float* __restrict__ W,
    const float* __restrict__ bias, float* __restrict__ Cout, int M, int N) {
  __shared__ float As[16][64];
  __shared__ float Bs[16][64];
  int tid = threadIdx.x;
  int m0 = blockIdx.x * 64;
  int n0 = blockIdx.y * 64;
  int ar = tid >> 2, ac = tid & 3;
  int br = tid >> 4, bc = tid & 15;
  int tm = tid >> 4, tn = tid & 15;
  float c[4][4] = {};
  for (int k0 = 0; k0 < K; k0 += 16) {
    float4 av = make_float4(0.f, 0.f, 0.f, 0.f);
    int arow = m0 + ar;
    if (arow < M) av = *reinterpret_cast<const float4*>(&A[(long)arow * K + k0 + ac * 4]);
    As[ac * 4 + 0][ar] = av.x;
    As[ac * 4 + 1][ar] = av.y;
    As[ac * 4 + 2][ar] = av.z;
    As[ac * 4 + 3][ar] = av.w;
    *reinterpret_cast<float4*>(&Bs[br][bc * 4]) =
        *reinterpret_cast<const float4*>(&W[(long)(k0 + br) * N + n0 + bc * 4]);
    __syncthreads();
    #pragma unroll
    for (int kk = 0; kk < 16; ++kk) {
      const float4 a4 = *reinterpret_cast<const float4*>(&As[kk][tm * 4]);
      const float4 b4 = *reinterpret_cast<const float4*>(&Bs[kk][tn * 4]);
      const float a[4] = {a4.x, a4.y, a4.z, a4.w};
      const float b[4] = {b4.x, b4.y, b4.z, b4.w};
      #pragma unroll
      for (int i = 0; i < 4; ++i)
        #pragma unroll
        for (int j = 0; j < 4; ++j)
          c[i][j] = fmaf(a[i], b[j], c[i][j]);
    }
    __syncthreads();
  }
  const float4 bb = *reinterpret_cast<const float4*>(&bias[n0 + tn * 4]);
  #pragma unroll
  for (int i = 0; i < 4; ++i) {
    int rowi = m0 + tm * 4 + i;
    if (rowi < M) {
      float4 o;
      o.x = fmaxf(c[i][0] + bb.x, 0.0f);
      o.y = fmaxf(c[i][1] + bb.y, 0.0f);
      o.z = fmaxf(c[i][2] + bb.z, 0.0f);
      o.w = fmaxf(c[i][3] + bb.w, 0.0f);
      *reinterpret_cast<float4*>(&Cout[(long)rowi * N + n0 + tn * 4]) = o;
    }
  }
}

// ---------------- mean pool (atomics) ----------------
__global__ void pool_kernel(const float* __restrict__ h, const int* __restrict__ batch,
                            float* __restrict__ gsum, int* __restrict__ gcnt, int n) {
  int i = blockIdx.x;
  int c = threadIdx.x;
  int b = batch[i];
  atomicAdd(&gsum[b * HIDC + c], h[(long)i * HIDC + c]);
  if (c == 0) atomicAdd(&gcnt[b], 1);
}

// ---------------- final MLP + log_softmax ----------------
__global__ __launch_bounds__(64) void mlp_kernel(
    const float* __restrict__ gsum, const int* __restrict__ gcnt,
    const float* __restrict__ Wl1, const float* __restrict__ bl1,
    const float* __restrict__ Wl2, const float* __restrict__ bl2,
    float* __restrict__ out) {
  __shared__ float g[HIDC];
  __shared__ float hid[64];
  __shared__ float logits[NCLS];
  __shared__ float red[2];
  int i = blockIdx.x;
  int t = threadIdx.x;
  float inv = 1.0f / fmaxf((float)gcnt[i], 1.0f);
  for (int c = t; c < HIDC; c += 64) g[c] = gsum[i * HIDC + c] * inv;
  __syncthreads();
  float acc = bl1[t];
  for (int c = 0; c < HIDC; ++c) acc = fmaf(g[c], Wl1[c * 64 + t], acc);
  hid[t] = fmaxf(acc, 0.0f);
  __syncthreads();
  if (t < NCLS) {
    float l = bl2[t];
    for (int c = 0; c < 64; ++c) l = fmaf(hid[c], Wl2[c * NCLS + t], l);
    logits[t] = l;
  }
  __syncthreads();
  if (t == 0) {
    float m = -1e30f;
    for (int k = 0; k < NCLS; ++k) m = fmaxf(m, logits[k]);
    float s = 0.f;
    for (int k = 0; k < NCLS; ++k) s += expf(logits[k] - m);
    red[0] = m;
    red[1] = logf(s);
  }
  __syncthreads();
  if (t < NCLS) out[i * NCLS + t] = logits[t] - red[0] - red[1];
}

extern "C" void kernel_launch(void* const* d_in, const int* in_sizes, int n_in,
                              void* d_out, int out_size, void* d_ws, size_t ws_size,
                              hipStream_t stream) {
  const float* x = (const float*)d_in[0];
  const int* edge_index = (const int*)d_in[1];
  const int* batch = (const int*)d_in[2];
  const float* W1 = (const float*)d_in[3];
  const float* b1 = (const float*)d_in[4];
  const float* W2 = (const float*)d_in[5];
  const float* b2 = (const float*)d_in[6];
  const float* Wl1 = (const float*)d_in[7];
  const float* bl1 = (const float*)d_in[8];
  const float* Wl2 = (const float*)d_in[9];
  const float* bl2 = (const float*)d_in[10];
  float* out = (float*)d_out;

  const int N = in_sizes[0] / INC;     // 50000
  const int E = in_sizes[1] / 2;       // 1600000
  const int* erow = edge_index;        // [E] sources
  const int* ecol = edge_index + E;    // [E] targets

  // workspace carving
  char* p = (char*)d_ws;
  auto alloc = [&](size_t bytes) {
    void* r = (void*)p;
    p += (bytes + 255) & ~(size_t)255;
    return r;
  };
  int* deg = (int*)alloc((size_t)N * 4);
  float* dis = (float*)alloc((size_t)N * 4);
  int* offsets = (int*)alloc((size_t)(N + 1) * 4);
  int* cursor = (int*)alloc((size_t)N * 4);
  int* rows_csr = (int*)alloc((size_t)E * 4);
  float* bufX = (float*)alloc((size_t)N * HIDC * 4);
  float* bufY = (float*)alloc((size_t)N * HIDC * 4);
  float* gsum = (float*)alloc((size_t)NG * HIDC * 4);
  int* gcnt = (int*)alloc((size_t)NG * 4);

  hipMemsetAsync(deg, 0, (size_t)N * 4, stream);
  hipMemsetAsync(gsum, 0, (size_t)NG * HIDC * 4, stream);
  hipMemsetAsync(gcnt, 0, (size_t)NG * 4, stream);

  count_deg<<<2048, 256, 0, stream>>>(ecol, deg, E);
  compute_dis<<<(N + 255) / 256, 256, 0, stream>>>(deg, dis, N);
  scan_offsets<<<1, SCAN_B, 0, stream>>>(deg, offsets, N);
  hipMemcpyAsync(cursor, offsets, (size_t)N * 4, hipMemcpyDeviceToDevice, stream);
  fill_csr<<<2048, 256, 0, stream>>>(erow, ecol, cursor, rows_csr, E);

  // layer 1: agg over x (128ch), then GEMM(128->256)+bias+relu
  aggregate<INC><<<N, INC, 0, stream>>>(x, dis, offsets, rows_csr, bufX);
  {
    dim3 grid((N + 63) / 64, HIDC / 64);
    gemm_bias_relu<INC><<<grid, 256, 0, stream>>>(bufX, W1, b1, bufY, N, HIDC);
  }
  // layer 2: agg over h1 (256ch), then GEMM(256->256)+bias+relu
  aggregate<HIDC><<<N, HIDC, 0, stream>>>(bufY, dis, offsets, rows_csr, bufX);
  {
    dim3 grid((N + 63) / 64, HIDC / 64);
    gemm_bias_relu<HIDC><<<grid, 256, 0, stream>>>(bufX, W2, b2, bufY, N, HIDC);
  }
  // mean pool
  pool_kernel<<<N, HIDC, 0, stream>>>(bufY, batch, gsum, gcnt, N);
  // final MLP + log_softmax
  mlp_kernel<<<NG, 64, 0, stream>>>(gsum, gcnt, Wl1, bl1, Wl2, bl2, out);
}

// Round 2
// 809.055 us; speedup vs baseline: 1.4003x; 1.4003x over previous
//
#include <hip/hip_runtime.h>
#include <hip/hip_bf16.h>
#include <math.h>

#define NN 50000
#define NG 128
#define INC 128
#define HIDC 256
#define NCLS 10

// ---------------- degree / normalization ----------------
__global__ void count_deg(const int* __restrict__ col, int* __restrict__ deg, int E) {
  int stride = gridDim.x * blockDim.x;
  for (int e = blockIdx.x * blockDim.x + threadIdx.x; e < E; e += stride)
    atomicAdd(&deg[col[e]], 1);
}

__global__ void compute_dis(const int* __restrict__ deg, float* __restrict__ dis, int n) {
  int i = blockIdx.x * blockDim.x + threadIdx.x;
  if (i < n) dis[i] = rsqrtf((float)deg[i] + 1.0f);
}

// ---------------- multi-block exclusive scan ----------------
// scanA: per-block inclusive scan of 2048 elements (256 thr x 8), block totals out
#define SCAN_T 256
#define SCAN_V 8
#define SCAN_VPB (SCAN_T * SCAN_V)  // 2048

__global__ __launch_bounds__(SCAN_T) void scanA(const int* __restrict__ deg,
                                                int* __restrict__ offsets,
                                                int* __restrict__ blockTotals, int n) {
  __shared__ int sm[SCAN_T];
  int b = blockIdx.x;
  int t = threadIdx.x;
  int base = b * SCAN_VPB + t * SCAN_V;
  int v[SCAN_V];
  int run = 0;
  #pragma unroll
  for (int j = 0; j < SCAN_V; ++j) {
    int idx = base + j;
    int d = (idx < n) ? deg[idx] : 0;
    run += d;
    v[j] = run;  // inclusive within thread
  }
  sm[t] = run;
  __syncthreads();
  // Hillis-Steele exclusive scan of thread totals
  #pragma unroll
  for (int off = 1; off < SCAN_T; off <<= 1) {
    int x = (t >= off) ? sm[t - off] : 0;
    __syncthreads();
    sm[t] += x;
    __syncthreads();
  }
  int excl = (t == 0) ? 0 : sm[t - 1];
  #pragma unroll
  for (int j = 0; j < SCAN_V; ++j) {
    int idx = base + j;
    if (idx < n) offsets[idx + 1] = v[j] + excl;  // inclusive within block
  }
  if (t == SCAN_T - 1) blockTotals[b] = sm[t];
}

__global__ void scanB(int* __restrict__ blockTotals, int nb) {
  // tiny: serial exclusive scan by one thread
  if (threadIdx.x == 0 && blockIdx.x == 0) {
    int run = 0;
    for (int i = 0; i < nb; ++i) {
      int v = blockTotals[i];
      blockTotals[i] = run;
      run += v;
    }
  }
}

__global__ void scanC(int* __restrict__ offsets, const int* __restrict__ blockTotals, int n) {
  int stride = gridDim.x * blockDim.x;
  for (int i = blockIdx.x * blockDim.x + threadIdx.x; i < n; i += stride) {
    offsets[i + 1] += blockTotals[i / SCAN_VPB];
    if (i == 0) offsets[0] = 0;
  }
}

__global__ void fill_csr(const int* __restrict__ row, const int* __restrict__ col,
                         int* __restrict__ cursor, int* __restrict__ rows_csr, int E) {
  int stride = gridDim.x * blockDim.x;
  for (int e = blockIdx.x * blockDim.x + threadIdx.x; e < E; e += stride) {
    int pos = atomicAdd(&cursor[col[e]], 1);
    rows_csr[pos] = row[e];
  }
}

// ---------------- aggregation: out[i] = sum_{e: col=i} x[row_e]*dis[row]*dis[i] + x[i]*dis[i]^2
template <int C>
__global__ void aggregate(const float* __restrict__ x, const float* __restrict__ dis,
                          const int* __restrict__ offsets, const int* __restrict__ rows_csr,
                          float* __restrict__ out) {
  int i = blockIdx.x;
  int c = threadIdx.x;
  float di = dis[i];
  float acc = x[(long)i * C + c] * di * di;
  int e0 = offsets[i], e1 = offsets[i + 1];
  int e = e0;
  for (; e + 1 < e1; e += 2) {
    int r0 = rows_csr[e];
    int r1 = rows_csr[e + 1];
    float s0 = dis[r0] * di;
    float s1 = dis[r1] * di;
    float v0 = x[(long)r0 * C + c];
    float v1 = x[(long)r1 * C + c];
    acc = fmaf(v0, s0, acc);
    acc = fmaf(v1, s1, acc);
  }
  if (e < e1) {
    int r0 = rows_csr[e];
    acc = fmaf(x[(long)r0 * C + c], dis[r0] * di, acc);
  }
  out[(long)i * C + c] = acc;
}

// ---------------- fused GEMM + bias + relu: Cout = relu(A[M,K] @ W[K,N] + b) ----------------
template <int K>
__global__ __launch_bounds__(256) void gemm_bias_relu(
    const float* __restrict__ A, const float* __restrict__ W,
    const float* __restrict__ bias, float* __restrict__ Cout, int M, int N) {
  __shared__ float As[16][64];
  __shared__ float Bs[16][64];
  int tid = threadIdx.x;
  int m0 = blockIdx.x * 64;
  int n0 = blockIdx.y * 64;
  int ar = tid >> 2, ac = tid & 3;
  int br = tid >> 4, bc = tid & 15;
  int tm = tid >> 4, tn = tid & 15;
  float c[4][4] = {};
  for (int k0 = 0; k0 < K; k0 += 16) {
    float4 av = make_float4(0.f, 0.f, 0.f, 0.f);
    int arow = m0 + ar;
    if (arow < M) av = *reinterpret_cast<const float4*>(&A[(long)arow * K + k0 + ac * 4]);
    As[ac * 4 + 0][ar] = av.x;
    As[ac * 4 + 1][ar] = av.y;
    As[ac * 4 + 2][ar] = av.z;
    As[ac * 4 + 3][ar] = av.w;
    *reinterpret_cast<float4*>(&Bs[br][bc * 4]) =
        *reinterpret_cast<const float4*>(&W[(long)(k0 + br) * N + n0 + bc * 4]);
    __syncthreads();
    #pragma unroll
    for (int kk = 0; kk < 16; ++kk) {
      const float4 a4 = *reinterpret_cast<const float4*>(&As[kk][tm * 4]);
      const float4 b4 = *reinterpret_cast<const float4*>(&Bs[kk][tn * 4]);
      const float a[4] = {a4.x, a4.y, a4.z, a4.w};
      const float b[4] = {b4.x, b4.y, b4.z, b4.w};
      #pragma unroll
      for (int i = 0; i < 4; ++i)
        #pragma unroll
        for (int j = 0; j < 4; ++j)
          c[i][j] = fmaf(a[i], b[j], c[i][j]);
    }
    __syncthreads();
  }
  const float4 bb = *reinterpret_cast<const float4*>(&bias[n0 + tn * 4]);
  #pragma unroll
  for (int i = 0; i < 4; ++i) {
    int rowi = m0 + tm * 4 + i;
    if (rowi < M) {
      float4 o;
      o.x = fmaxf(c[i][0] + bb.x, 0.0f);
      o.y = fmaxf(c[i][1] + bb.y, 0.0f);
      o.z = fmaxf(c[i][2] + bb.z, 0.0f);
      o.w = fmaxf(c[i][3] + bb.w, 0.0f);
      *reinterpret_cast<float4*>(&Cout[(long)rowi * N + n0 + tn * 4]) = o;
    }
  }
}

// ---------------- pool via sorted-batch ranges ----------------
__global__ void find_bounds(const int* __restrict__ batch, int* __restrict__ gstart, int n) {
  int stride = gridDim.x * blockDim.x;
  for (int i = blockIdx.x * blockDim.x + threadIdx.x; i < n; i += stride) {
    int b = batch[i];
    if (i == 0) {
      for (int g = 0; g <= b; ++g) gstart[g] = 0;
    } else {
      int pb = batch[i - 1];
      if (pb != b)
        for (int g = pb + 1; g <= b; ++g) gstart[g] = i;
    }
    if (i == n - 1) {
      for (int g = b + 1; g <= NG; ++g) gstart[g] = n;
    }
  }
}

#define POOL_SPLIT 8
__global__ __launch_bounds__(HIDC) void pool_range(const float* __restrict__ h,
                                                   const int* __restrict__ gstart,
                                                   float* __restrict__ gsum) {
  int g = blockIdx.x;
  int s = blockIdx.y;
  int c = threadIdx.x;
  int s0 = gstart[g], s1 = gstart[g + 1];
  int len = s1 - s0;
  int chunk = (len + POOL_SPLIT - 1) / POOL_SPLIT;
  int i0 = s0 + s * chunk;
  int i1 = min(i0 + chunk, s1);
  float acc = 0.0f;
  for (int i = i0; i < i1; ++i) acc += h[(long)i * HIDC + c];
  if (i1 > i0) atomicAdd(&gsum[g * HIDC + c], acc);
}

// ---------------- final MLP + log_softmax ----------------
__global__ __launch_bounds__(64) void mlp_kernel(
    const float* __restrict__ gsum, const int* __restrict__ gstart,
    const float* __restrict__ Wl1, const float* __restrict__ bl1,
    const float* __restrict__ Wl2, const float* __restrict__ bl2,
    float* __restrict__ out) {
  __shared__ float g[HIDC];
  __shared__ float hid[64];
  __shared__ float logits[NCLS];
  __shared__ float red[2];
  int i = blockIdx.x;
  int t = threadIdx.x;
  int cnt = gstart[i + 1] - gstart[i];
  float inv = 1.0f / fmaxf((float)cnt, 1.0f);
  for (int c = t; c < HIDC; c += 64) g[c] = gsum[i * HIDC + c] * inv;
  __syncthreads();
  float acc = bl1[t];
  for (int c = 0; c < HIDC; ++c) acc = fmaf(g[c], Wl1[c * 64 + t], acc);
  hid[t] = fmaxf(acc, 0.0f);
  __syncthreads();
  if (t < NCLS) {
    float l = bl2[t];
    for (int c = 0; c < 64; ++c) l = fmaf(hid[c], Wl2[c * NCLS + t], l);
    logits[t] = l;
  }
  __syncthreads();
  if (t == 0) {
    float m = -1e30f;
    for (int k = 0; k < NCLS; ++k) m = fmaxf(m, logits[k]);
    float s = 0.f;
    for (int k = 0; k < NCLS; ++k) s += expf(logits[k] - m);
    red[0] = m;
    red[1] = logf(s);
  }
  __syncthreads();
  if (t < NCLS) out[i * NCLS + t] = logits[t] - red[0] - red[1];
}

extern "C" void kernel_launch(void* const* d_in, const int* in_sizes, int n_in,
                              void* d_out, int out_size, void* d_ws, size_t ws_size,
                              hipStream_t stream) {
  const float* x = (const float*)d_in[0];
  const int* edge_index = (const int*)d_in[1];
  const int* batch = (const int*)d_in[2];
  const float* W1 = (const float*)d_in[3];
  const float* b1 = (const float*)d_in[4];
  const float* W2 = (const float*)d_in[5];
  const float* b2 = (const float*)d_in[6];
  const float* Wl1 = (const float*)d_in[7];
  const float* bl1 = (const float*)d_in[8];
  const float* Wl2 = (const float*)d_in[9];
  const float* bl2 = (const float*)d_in[10];
  float* out = (float*)d_out;

  const int N = in_sizes[0] / INC;     // 50000
  const int E = in_sizes[1] / 2;       // 1600000
  const int* erow = edge_index;        // [E] sources
  const int* ecol = edge_index + E;    // [E] targets

  // workspace carving
  char* p = (char*)d_ws;
  auto alloc = [&](size_t bytes) {
    void* r = (void*)p;
    p += (bytes + 255) & ~(size_t)255;
    return r;
  };
  int* deg = (int*)alloc((size_t)N * 4);
  float* dis = (float*)alloc((size_t)N * 4);
  int* offsets = (int*)alloc((size_t)(N + 1) * 4);
  int* cursor = (int*)alloc((size_t)N * 4);
  int* rows_csr = (int*)alloc((size_t)E * 4);
  float* bufX = (float*)alloc((size_t)N * HIDC * 4);
  float* bufY = (float*)alloc((size_t)N * HIDC * 4);
  float* gsum = (float*)alloc((size_t)NG * HIDC * 4);
  int* gstart = (int*)alloc((size_t)(NG + 1) * 4);
  int* blockTotals = (int*)alloc((size_t)256 * 4);

  hipMemsetAsync(deg, 0, (size_t)N * 4, stream);
  hipMemsetAsync(gsum, 0, (size_t)NG * HIDC * 4, stream);

  count_deg<<<2048, 256, 0, stream>>>(ecol, deg, E);
  compute_dis<<<(N + 255) / 256, 256, 0, stream>>>(deg, dis, N);

  const int nb = (N + SCAN_VPB - 1) / SCAN_VPB;  // 25
  scanA<<<nb, SCAN_T, 0, stream>>>(deg, offsets, blockTotals, N);
  scanB<<<1, 64, 0, stream>>>(blockTotals, nb);
  scanC<<<(N + 255) / 256, 256, 0, stream>>>(offsets, blockTotals, N);

  hipMemcpyAsync(cursor, offsets, (size_t)N * 4, hipMemcpyDeviceToDevice, stream);
  fill_csr<<<2048, 256, 0, stream>>>(erow, ecol, cursor, rows_csr, E);

  // layer 1: agg over x (128ch), then GEMM(128->256)+bias+relu
  aggregate<INC><<<N, INC, 0, stream>>>(x, dis, offsets, rows_csr, bufX);
  {
    dim3 grid((N + 63) / 64, HIDC / 64);
    gemm_bias_relu<INC><<<grid, 256, 0, stream>>>(bufX, W1, b1, bufY, N, HIDC);
  }
  // layer 2: agg over h1 (256ch), then GEMM(256->256)+bias+relu
  aggregate<HIDC><<<N, HIDC, 0, stream>>>(bufY, dis, offsets, rows_csr, bufX);
  {
    dim3 grid((N + 63) / 64, HIDC / 64);
    gemm_bias_relu<HIDC><<<grid, 256, 0, stream>>>(bufX, W2, b2, bufY, N, HIDC);
  }
  // pool via sorted ranges
  find_bounds<<<(N + 255) / 256, 256, 0, stream>>>(batch, gstart, N);
  {
    dim3 pgrid(NG, POOL_SPLIT);
    pool_range<<<pgrid, HIDC, 0, stream>>>(bufY, gstart, gsum);
  }
  // final MLP + log_softmax
  mlp_kernel<<<NG, 64, 0, stream>>>(gsum, gstart, Wl1, bl1, Wl2, bl2, out);
}

// Round 3
// 625.311 us; speedup vs baseline: 1.8118x; 1.2938x over previous
//
#include <hip/hip_runtime.h>
#include <hip/hip_bf16.h>
#include <math.h>

#define NN 50000
#define NG 128
#define INC 128
#define HIDC 256
#define NCLS 10

typedef __attribute__((ext_vector_type(8))) short s8_t;    // 8 bf16 (4 VGPR)
typedef __attribute__((ext_vector_type(4))) float f4_t;    // 4 f32

__device__ inline f4_t mfma16(s8_t a, s8_t b, f4_t c) {
  return __builtin_amdgcn_mfma_f32_16x16x32_bf16(a, b, c, 0, 0, 0);
}

__device__ inline float bf2f(ushort u) {
  union { unsigned int i; float f; } c; c.i = ((unsigned int)u) << 16; return c.f;
}
__device__ inline ushort f2bf(float f) {
  __hip_bfloat16 h = __float2bfloat16(f);
  return *(ushort*)&h;
}

__device__ inline void gload_lds16(const void* g, void* l) {
  __builtin_amdgcn_global_load_lds(
      (const __attribute__((address_space(1))) unsigned int*)g,
      (__attribute__((address_space(3))) unsigned int*)l, 16, 0, 0);
}

// ---------------- degree / normalization ----------------
__global__ void count_deg(const int* __restrict__ col, int* __restrict__ deg, int E) {
  int stride = gridDim.x * blockDim.x;
  for (int e = blockIdx.x * blockDim.x + threadIdx.x; e < E; e += stride)
    atomicAdd(&deg[col[e]], 1);
}

__global__ void compute_dis(const int* __restrict__ deg, float* __restrict__ dis, int n) {
  int i = blockIdx.x * blockDim.x + threadIdx.x;
  if (i < n) dis[i] = rsqrtf((float)deg[i] + 1.0f);
}

// ---------------- multi-block exclusive scan ----------------
#define SCAN_T 256
#define SCAN_V 8
#define SCAN_VPB (SCAN_T * SCAN_V)  // 2048

__global__ __launch_bounds__(SCAN_T) void scanA(const int* __restrict__ deg,
                                                int* __restrict__ offsets,
                                                int* __restrict__ blockTotals, int n) {
  __shared__ int sm[SCAN_T];
  int b = blockIdx.x;
  int t = threadIdx.x;
  int base = b * SCAN_VPB + t * SCAN_V;
  int v[SCAN_V];
  int run = 0;
  #pragma unroll
  for (int j = 0; j < SCAN_V; ++j) {
    int idx = base + j;
    int d = (idx < n) ? deg[idx] : 0;
    run += d;
    v[j] = run;
  }
  sm[t] = run;
  __syncthreads();
  #pragma unroll
  for (int off = 1; off < SCAN_T; off <<= 1) {
    int x = (t >= off) ? sm[t - off] : 0;
    __syncthreads();
    sm[t] += x;
    __syncthreads();
  }
  int excl = (t == 0) ? 0 : sm[t - 1];
  #pragma unroll
  for (int j = 0; j < SCAN_V; ++j) {
    int idx = base + j;
    if (idx < n) offsets[idx + 1] = v[j] + excl;
  }
  if (t == SCAN_T - 1) blockTotals[b] = sm[t];
}

__global__ void scanB(int* __restrict__ blockTotals, int nb) {
  if (threadIdx.x == 0 && blockIdx.x == 0) {
    int run = 0;
    for (int i = 0; i < nb; ++i) {
      int v = blockTotals[i];
      blockTotals[i] = run;
      run += v;
    }
  }
}

__global__ void scanC(int* __restrict__ offsets, const int* __restrict__ blockTotals, int n) {
  int stride = gridDim.x * blockDim.x;
  for (int i = blockIdx.x * blockDim.x + threadIdx.x; i < n; i += stride) {
    offsets[i + 1] += blockTotals[i / SCAN_VPB];
    if (i == 0) offsets[0] = 0;
  }
}

__global__ void fill_csr(const int* __restrict__ row, const int* __restrict__ col,
                         int* __restrict__ cursor, int* __restrict__ rows_csr, int E) {
  int stride = gridDim.x * blockDim.x;
  for (int e = blockIdx.x * blockDim.x + threadIdx.x; e < E; e += stride) {
    int pos = atomicAdd(&cursor[col[e]], 1);
    rows_csr[pos] = row[e];
  }
}

// ---------------- casts ----------------
__global__ void cast_f32_bf16(const float* __restrict__ in, ushort* __restrict__ out, int n4) {
  int i = blockIdx.x * blockDim.x + threadIdx.x;
  if (i < n4) {
    float4 v = ((const float4*)in)[i];
    ushort4 o;
    o.x = f2bf(v.x); o.y = f2bf(v.y); o.z = f2bf(v.z); o.w = f2bf(v.w);
    ((ushort4*)out)[i] = o;
  }
}

// WT[n*K+k] = bf16(W[k*N+n])
__global__ void transpose_cast(const float* __restrict__ W, ushort* __restrict__ WT,
                               int K, int N) {
  int idx = blockIdx.x * blockDim.x + threadIdx.x;
  if (idx < K * N) {
    int k = idx / N, n = idx % N;
    WT[(long)n * K + k] = f2bf(W[idx]);
  }
}

// ---------------- aggregation (bf16 in/out, fp32 accum) ----------------
// one wave per node; row = 64 x 4B (C=128) or 64 x 8B (C=256)
__global__ __launch_bounds__(256) void aggregate128_bf16(
    const ushort* __restrict__ xb, const float* __restrict__ dis,
    const int* __restrict__ offsets, const int* __restrict__ rows_csr,
    ushort* __restrict__ outb, int N) {
  int node = blockIdx.x * 4 + (threadIdx.x >> 6);
  if (node >= N) return;
  int lane = threadIdx.x & 63;
  float di = dis[node];
  const unsigned int* xv = (const unsigned int*)xb;  // 64 uints per row
  unsigned int sv = xv[(long)node * 64 + lane];
  float a0 = bf2f((ushort)sv) * di * di;
  float a1 = bf2f((ushort)(sv >> 16)) * di * di;
  int e0 = offsets[node], e1 = offsets[node + 1];
  int e = e0;
  for (; e + 1 < e1; e += 2) {
    int r0 = rows_csr[e], r1 = rows_csr[e + 1];
    float s0 = dis[r0] * di, s1 = dis[r1] * di;
    unsigned int v0 = xv[(long)r0 * 64 + lane];
    unsigned int v1 = xv[(long)r1 * 64 + lane];
    a0 = fmaf(bf2f((ushort)v0), s0, a0);
    a1 = fmaf(bf2f((ushort)(v0 >> 16)), s0, a1);
    a0 = fmaf(bf2f((ushort)v1), s1, a0);
    a1 = fmaf(bf2f((ushort)(v1 >> 16)), s1, a1);
  }
  if (e < e1) {
    int r0 = rows_csr[e];
    float s0 = dis[r0] * di;
    unsigned int v0 = xv[(long)r0 * 64 + lane];
    a0 = fmaf(bf2f((ushort)v0), s0, a0);
    a1 = fmaf(bf2f((ushort)(v0 >> 16)), s0, a1);
  }
  unsigned int o = (unsigned int)f2bf(a0) | ((unsigned int)f2bf(a1) << 16);
  ((unsigned int*)outb)[(long)node * 64 + lane] = o;
}

__global__ __launch_bounds__(256) void aggregate256_bf16(
    const ushort* __restrict__ xb, const float* __restrict__ dis,
    const int* __restrict__ offsets, const int* __restrict__ rows_csr,
    ushort* __restrict__ outb, int N) {
  int node = blockIdx.x * 4 + (threadIdx.x >> 6);
  if (node >= N) return;
  int lane = threadIdx.x & 63;
  float di = dis[node];
  const uint2* xv = (const uint2*)xb;  // 64 uint2 per row
  uint2 sv = xv[(long)node * 64 + lane];
  float a0 = bf2f((ushort)sv.x) * di * di;
  float a1 = bf2f((ushort)(sv.x >> 16)) * di * di;
  float a2 = bf2f((ushort)sv.y) * di * di;
  float a3 = bf2f((ushort)(sv.y >> 16)) * di * di;
  int e0 = offsets[node], e1 = offsets[node + 1];
  int e = e0;
  for (; e + 1 < e1; e += 2) {
    int r0 = rows_csr[e], r1 = rows_csr[e + 1];
    float s0 = dis[r0] * di, s1 = dis[r1] * di;
    uint2 v0 = xv[(long)r0 * 64 + lane];
    uint2 v1 = xv[(long)r1 * 64 + lane];
    a0 = fmaf(bf2f((ushort)v0.x), s0, a0);
    a1 = fmaf(bf2f((ushort)(v0.x >> 16)), s0, a1);
    a2 = fmaf(bf2f((ushort)v0.y), s0, a2);
    a3 = fmaf(bf2f((ushort)(v0.y >> 16)), s0, a3);
    a0 = fmaf(bf2f((ushort)v1.x), s1, a0);
    a1 = fmaf(bf2f((ushort)(v1.x >> 16)), s1, a1);
    a2 = fmaf(bf2f((ushort)v1.y), s1, a2);
    a3 = fmaf(bf2f((ushort)(v1.y >> 16)), s1, a3);
  }
  if (e < e1) {
    int r0 = rows_csr[e];
    float s0 = dis[r0] * di;
    uint2 v0 = xv[(long)r0 * 64 + lane];
    a0 = fmaf(bf2f((ushort)v0.x), s0, a0);
    a1 = fmaf(bf2f((ushort)(v0.x >> 16)), s0, a1);
    a2 = fmaf(bf2f((ushort)v0.y), s0, a2);
    a3 = fmaf(bf2f((ushort)(v0.y >> 16)), s0, a3);
  }
  uint2 o;
  o.x = (unsigned int)f2bf(a0) | ((unsigned int)f2bf(a1) << 16);
  o.y = (unsigned int)f2bf(a2) | ((unsigned int)f2bf(a3) << 16);
  ((uint2*)outb)[(long)node * 64 + lane] = o;
}

// ---------------- MFMA GEMM: Cout = relu(A[M,K]bf16 @ W[K,256]bf16 + b) ----------------
// tile 128x128, BK=64, 4 waves (2x2), each wave 64x64 (4x4 frags of 16x16x32)
// LDS: As[128 rows][64 bf16] + Bs(=WT rows)[128][64], XOR-swizzled 16B chunks
template <int K, bool OUTBF16>
__global__ __launch_bounds__(256) void gemm_mfma(
    const ushort* __restrict__ A, const ushort* __restrict__ WT,
    const float* __restrict__ bias, ushort* __restrict__ outb,
    float* __restrict__ outf, int M) {
  __shared__ ushort smem[16384];  // 32 KB: A at 0, B at 8192 (ushort units)
  const int tid = threadIdx.x;
  const int lane = tid & 63;
  const int wave = tid >> 6;
  const int wm = wave >> 1, wn = wave & 1;
  const int m0 = blockIdx.x * 128;
  const int n0 = blockIdx.y * 128;

  f4_t acc[4][4] = {};

  for (int k0 = 0; k0 < K; k0 += 64) {
    __syncthreads();
    // stage A tile [128][64] : slot s = row*8 + chunk, content chunk = slot^ (row&7)
    #pragma unroll
    for (int is = 0; is < 4; ++is) {
      int s = is * 256 + tid;
      int row = s >> 3;
      int ch = (s & 7) ^ (row & 7);
      long grow = m0 + row; if (grow > M - 1) grow = M - 1;
      const ushort* g = A + grow * K + k0 + ch * 8;
      gload_lds16(g, &smem[(is * 256 + wave * 64) * 8]);
    }
    // stage B tile (WT rows n0..n0+127)
    #pragma unroll
    for (int is = 0; is < 4; ++is) {
      int s = is * 256 + tid;
      int row = s >> 3;
      int ch = (s & 7) ^ (row & 7);
      const ushort* g = WT + (long)(n0 + row) * K + k0 + ch * 8;
      gload_lds16(g, &smem[8192 + (is * 256 + wave * 64) * 8]);
    }
    asm volatile("s_waitcnt vmcnt(0)" ::: "memory");
    __syncthreads();
    #pragma unroll
    for (int ks = 0; ks < 2; ++ks) {
      s8_t af[4], bfr[4];
      #pragma unroll
      for (int mi = 0; mi < 4; ++mi) {
        int row = wm * 64 + mi * 16 + (lane & 15);
        int ch = (ks * 4 + (lane >> 4)) ^ (row & 7);
        af[mi] = *(const s8_t*)(&smem[row * 64 + ch * 8]);
      }
      #pragma unroll
      for (int ni = 0; ni < 4; ++ni) {
        int row = wn * 64 + ni * 16 + (lane & 15);
        int ch = (ks * 4 + (lane >> 4)) ^ (row & 7);
        bfr[ni] = *(const s8_t*)(&smem[8192 + row * 64 + ch * 8]);
      }
      #pragma unroll
      for (int mi = 0; mi < 4; ++mi)
        #pragma unroll
        for (int ni = 0; ni < 4; ++ni)
          acc[mi][ni] = mfma16(af[mi], bfr[ni], acc[mi][ni]);
    }
  }
  // epilogue: D col=lane&15, row=(lane>>4)*4+r  (m89-verified)
  #pragma unroll
  for (int ni = 0; ni < 4; ++ni) {
    int col = n0 + wn * 64 + ni * 16 + (lane & 15);
    float bb = bias[col];
    #pragma unroll
    for (int mi = 0; mi < 4; ++mi) {
      #pragma unroll
      for (int r = 0; r < 4; ++r) {
        int row = m0 + wm * 64 + mi * 16 + (lane >> 4) * 4 + r;
        if (row < M) {
          float v = fmaxf(acc[mi][ni][r] + bb, 0.0f);
          if (OUTBF16) outb[(long)row * HIDC + col] = f2bf(v);
          else outf[(long)row * HIDC + col] = v;
        }
      }
    }
  }
}

// ---------------- pool via sorted-batch ranges (bf16 input) ----------------
__global__ void find_bounds(const int* __restrict__ batch, int* __restrict__ gstart, int n) {
  int stride = gridDim.x * blockDim.x;
  for (int i = blockIdx.x * blockDim.x + threadIdx.x; i < n; i += stride) {
    int b = batch[i];
    if (i == 0) {
      for (int g = 0; g <= b; ++g) gstart[g] = 0;
    } else {
      int pb = batch[i - 1];
      if (pb != b)
        for (int g = pb + 1; g <= b; ++g) gstart[g] = i;
    }
    if (i == n - 1) {
      for (int g = b + 1; g <= NG; ++g) gstart[g] = n;
    }
  }
}

#define POOL_SPLIT 8
__global__ __launch_bounds__(HIDC) void pool_range_bf16(const ushort* __restrict__ h,
                                                        const int* __restrict__ gstart,
                                                        float* __restrict__ gsum) {
  int g = blockIdx.x;
  int s = blockIdx.y;
  int c = threadIdx.x;
  int s0 = gstart[g], s1 = gstart[g + 1];
  int len = s1 - s0;
  int chunk = (len + POOL_SPLIT - 1) / POOL_SPLIT;
  int i0 = s0 + s * chunk;
  int i1 = min(i0 + chunk, s1);
  float acc = 0.0f;
  for (int i = i0; i < i1; ++i) acc += bf2f(h[(long)i * HIDC + c]);
  if (i1 > i0) atomicAdd(&gsum[g * HIDC + c], acc);
}

// ---------------- final MLP + log_softmax ----------------
__global__ __launch_bounds__(64) void mlp_kernel(
    const float* __restrict__ gsum, const int* __restrict__ gstart,
    const float* __restrict__ Wl1, const float* __restrict__ bl1,
    const float* __restrict__ Wl2, const float* __restrict__ bl2,
    float* __restrict__ out) {
  __shared__ float g[HIDC];
  __shared__ float hid[64];
  __shared__ float logits[NCLS];
  __shared__ float red[2];
  int i = blockIdx.x;
  int t = threadIdx.x;
  int cnt = gstart[i + 1] - gstart[i];
  float inv = 1.0f / fmaxf((float)cnt, 1.0f);
  for (int c = t; c < HIDC; c += 64) g[c] = gsum[i * HIDC + c] * inv;
  __syncthreads();
  float acc = bl1[t];
  for (int c = 0; c < HIDC; ++c) acc = fmaf(g[c], Wl1[c * 64 + t], acc);
  hid[t] = fmaxf(acc, 0.0f);
  __syncthreads();
  if (t < NCLS) {
    float l = bl2[t];
    for (int c = 0; c < 64; ++c) l = fmaf(hid[c], Wl2[c * NCLS + t], l);
    logits[t] = l;
  }
  __syncthreads();
  if (t == 0) {
    float m = -1e30f;
    for (int k = 0; k < NCLS; ++k) m = fmaxf(m, logits[k]);
    float s = 0.f;
    for (int k = 0; k < NCLS; ++k) s += expf(logits[k] - m);
    red[0] = m;
    red[1] = logf(s);
  }
  __syncthreads();
  if (t < NCLS) out[i * NCLS + t] = logits[t] - red[0] - red[1];
}

extern "C" void kernel_launch(void* const* d_in, const int* in_sizes, int n_in,
                              void* d_out, int out_size, void* d_ws, size_t ws_size,
                              hipStream_t stream) {
  const float* x = (const float*)d_in[0];
  const int* edge_index = (const int*)d_in[1];
  const int* batch = (const int*)d_in[2];
  const float* W1 = (const float*)d_in[3];
  const float* b1 = (const float*)d_in[4];
  const float* W2 = (const float*)d_in[5];
  const float* b2 = (const float*)d_in[6];
  const float* Wl1 = (const float*)d_in[7];
  const float* bl1 = (const float*)d_in[8];
  const float* Wl2 = (const float*)d_in[9];
  const float* bl2 = (const float*)d_in[10];
  float* out = (float*)d_out;

  const int N = in_sizes[0] / INC;     // 50000
  const int E = in_sizes[1] / 2;       // 1600000
  const int* erow = edge_index;
  const int* ecol = edge_index + E;

  char* p = (char*)d_ws;
  auto alloc = [&](size_t bytes) {
    void* r = (void*)p;
    p += (bytes + 255) & ~(size_t)255;
    return r;
  };
  int* deg = (int*)alloc((size_t)N * 4);
  float* dis = (float*)alloc((size_t)N * 4);
  int* offsets = (int*)alloc((size_t)(N + 1) * 4);
  int* cursor = (int*)alloc((size_t)N * 4);
  int* rows_csr = (int*)alloc((size_t)E * 4);
  float* gsum = (float*)alloc((size_t)NG * HIDC * 4);
  int* gstart = (int*)alloc((size_t)(NG + 1) * 4);
  int* blockTotals = (int*)alloc((size_t)256 * 4);
  ushort* W1T = (ushort*)alloc((size_t)INC * HIDC * 2);
  ushort* W2T = (ushort*)alloc((size_t)HIDC * HIDC * 2);
  ushort* xb = (ushort*)alloc((size_t)N * INC * 2);      // 12.8 MB
  ushort* agg1b = (ushort*)alloc((size_t)N * INC * 2);   // 12.8 MB (contiguous after xb)
  ushort* h1b = (ushort*)alloc((size_t)N * HIDC * 2);    // 25.6 MB
  ushort* agg2b = (ushort*)alloc((size_t)N * HIDC * 2);  // 25.6 MB
  ushort* h2b = xb;  // reuse xb+agg1b region (both dead after GEMM1): 25.6 MB

  hipMemsetAsync(deg, 0, (size_t)N * 4, stream);
  hipMemsetAsync(gsum, 0, (size_t)NG * HIDC * 4, stream);

  count_deg<<<2048, 256, 0, stream>>>(ecol, deg, E);
  compute_dis<<<(N + 255) / 256, 256, 0, stream>>>(deg, dis, N);

  const int nb = (N + SCAN_VPB - 1) / SCAN_VPB;
  scanA<<<nb, SCAN_T, 0, stream>>>(deg, offsets, blockTotals, N);
  scanB<<<1, 64, 0, stream>>>(blockTotals, nb);
  scanC<<<(N + 255) / 256, 256, 0, stream>>>(offsets, blockTotals, N);

  hipMemcpyAsync(cursor, offsets, (size_t)N * 4, hipMemcpyDeviceToDevice, stream);
  fill_csr<<<2048, 256, 0, stream>>>(erow, ecol, cursor, rows_csr, E);

  // casts
  cast_f32_bf16<<<(N * INC / 4 + 255) / 256, 256, 0, stream>>>(x, xb, N * INC / 4);
  transpose_cast<<<(INC * HIDC + 255) / 256, 256, 0, stream>>>(W1, W1T, INC, HIDC);
  transpose_cast<<<(HIDC * HIDC + 255) / 256, 256, 0, stream>>>(W2, W2T, HIDC, HIDC);

  // layer 1
  aggregate128_bf16<<<(N + 3) / 4, 256, 0, stream>>>(xb, dis, offsets, rows_csr, agg1b, N);
  {
    dim3 grid((N + 127) / 128, HIDC / 128);
    gemm_mfma<INC, true><<<grid, 256, 0, stream>>>(agg1b, W1T, b1, h1b, nullptr, N);
  }
  // layer 2
  aggregate256_bf16<<<(N + 3) / 4, 256, 0, stream>>>(h1b, dis, offsets, rows_csr, agg2b, N);
  {
    dim3 grid((N + 127) / 128, HIDC / 128);
    gemm_mfma<HIDC, true><<<grid, 256, 0, stream>>>(agg2b, W2T, b2, h2b, nullptr, N);
  }
  // pool + MLP
  find_bounds<<<(N + 255) / 256, 256, 0, stream>>>(batch, gstart, N);
  {
    dim3 pgrid(NG, POOL_SPLIT);
    pool_range_bf16<<<pgrid, HIDC, 0, stream>>>(h2b, gstart, gsum);
  }
  mlp_kernel<<<NG, 64, 0, stream>>>(gsum, gstart, Wl1, bl1, Wl2, bl2, out);
}

// Round 4
// 419.935 us; speedup vs baseline: 2.6979x; 1.4891x over previous
//
#include <hip/hip_runtime.h>
#include <hip/hip_bf16.h>
#include <math.h>

#define NN 50000
#define NG 128
#define INC 128
#define HIDC 256
#define NCLS 10

#define NBLK 256   // partition chunks
#define BSH 8      // bucket = col >> 8
#define NB 196     // ceil(50000/256) buckets

typedef __attribute__((ext_vector_type(8))) short s8_t;    // 8 bf16 (4 VGPR)
typedef __attribute__((ext_vector_type(4))) float f4_t;    // 4 f32

__device__ inline f4_t mfma16(s8_t a, s8_t b, f4_t c) {
  return __builtin_amdgcn_mfma_f32_16x16x32_bf16(a, b, c, 0, 0, 0);
}

__device__ inline float bf2f(ushort u) {
  union { unsigned int i; float f; } c; c.i = ((unsigned int)u) << 16; return c.f;
}
__device__ inline ushort f2bf(float f) {
  __hip_bfloat16 h = __float2bfloat16(f);
  return *(ushort*)&h;
}

__device__ inline void gload_lds16(const void* g, void* l) {
  __builtin_amdgcn_global_load_lds(
      (const __attribute__((address_space(1))) unsigned int*)g,
      (__attribute__((address_space(3))) unsigned int*)l, 16, 0, 0);
}

// ---------------- bucketed edge partition ----------------
__global__ __launch_bounds__(256) void edge_hist(const int* __restrict__ ecol,
                                                 int* __restrict__ hist, int E, int chunk) {
  __shared__ int h[NB];
  int blk = blockIdx.x;
  for (int i = threadIdx.x; i < NB; i += 256) h[i] = 0;
  __syncthreads();
  int e0 = blk * chunk, e1 = min(e0 + chunk, E);
  for (int e = e0 + threadIdx.x; e < e1; e += 256)
    atomicAdd(&h[ecol[e] >> BSH], 1);
  __syncthreads();
  for (int i = threadIdx.x; i < NB; i += 256) hist[i * NBLK + blk] = h[i];
}

__global__ __launch_bounds__(256) void edge_partition(const int* __restrict__ erow,
                                                      const int* __restrict__ ecol,
                                                      const int* __restrict__ histBase,
                                                      uint2* __restrict__ part,
                                                      int E, int chunk) {
  __shared__ int cur[NB];
  int blk = blockIdx.x;
  for (int i = threadIdx.x; i < NB; i += 256) cur[i] = histBase[i * NBLK + blk];
  __syncthreads();
  int e0 = blk * chunk, e1 = min(e0 + chunk, E);
  for (int e = e0 + threadIdx.x; e < e1; e += 256) {
    int c = ecol[e];
    int b = c >> BSH;
    int pos = atomicAdd(&cur[b], 1);
    part[pos] = make_uint2((unsigned)erow[e], (unsigned)c);
  }
}

__global__ __launch_bounds__(256) void bucket_deg(const uint2* __restrict__ part,
                                                  const int* __restrict__ histBase,
                                                  int* __restrict__ deg, int N) {
  __shared__ int cnt[256];
  int b = blockIdx.x;
  cnt[threadIdx.x] = 0;
  __syncthreads();
  int s0 = histBase[b * NBLK];
  int s1 = histBase[(b + 1) * NBLK];
  for (int e = s0 + threadIdx.x; e < s1; e += 256)
    atomicAdd(&cnt[part[e].y & 255], 1);
  __syncthreads();
  int node = (b << BSH) + threadIdx.x;
  if (node < N) deg[node] = cnt[threadIdx.x];
}

__global__ __launch_bounds__(256) void bucket_csr(const uint2* __restrict__ part,
                                                  const int* __restrict__ histBase,
                                                  const int* __restrict__ offsets,
                                                  int* __restrict__ rows_csr, int N) {
  __shared__ int cur[256];
  int b = blockIdx.x;
  int node = (b << BSH) + threadIdx.x;
  cur[threadIdx.x] = (node < N) ? offsets[node] : 0;
  __syncthreads();
  int s0 = histBase[b * NBLK];
  int s1 = histBase[(b + 1) * NBLK];
  for (int e = s0 + threadIdx.x; e < s1; e += 256) {
    uint2 p = part[e];
    int pos = atomicAdd(&cur[p.y & 255], 1);
    rows_csr[pos] = (int)p.x;
  }
}

__global__ void compute_dis(const int* __restrict__ deg, float* __restrict__ dis, int n) {
  int i = blockIdx.x * blockDim.x + threadIdx.x;
  if (i < n) dis[i] = rsqrtf((float)deg[i] + 1.0f);
}

// ---------------- multi-block exclusive scan ----------------
#define SCAN_T 256
#define SCAN_V 8
#define SCAN_VPB (SCAN_T * SCAN_V)  // 2048

__global__ __launch_bounds__(SCAN_T) void scanA(const int* __restrict__ deg,
                                                int* __restrict__ offsets,
                                                int* __restrict__ blockTotals, int n) {
  __shared__ int sm[SCAN_T];
  int b = blockIdx.x;
  int t = threadIdx.x;
  int base = b * SCAN_VPB + t * SCAN_V;
  int v[SCAN_V];
  int run = 0;
  #pragma unroll
  for (int j = 0; j < SCAN_V; ++j) {
    int idx = base + j;
    int d = (idx < n) ? deg[idx] : 0;
    run += d;
    v[j] = run;
  }
  sm[t] = run;
  __syncthreads();
  #pragma unroll
  for (int off = 1; off < SCAN_T; off <<= 1) {
    int x = (t >= off) ? sm[t - off] : 0;
    __syncthreads();
    sm[t] += x;
    __syncthreads();
  }
  int excl = (t == 0) ? 0 : sm[t - 1];
  #pragma unroll
  for (int j = 0; j < SCAN_V; ++j) {
    int idx = base + j;
    if (idx < n) offsets[idx + 1] = v[j] + excl;
  }
  if (t == SCAN_T - 1) blockTotals[b] = sm[t];
}

__global__ void scanB(int* __restrict__ blockTotals, int nb) {
  if (threadIdx.x == 0 && blockIdx.x == 0) {
    int run = 0;
    for (int i = 0; i < nb; ++i) {
      int v = blockTotals[i];
      blockTotals[i] = run;
      run += v;
    }
  }
}

__global__ void scanC(int* __restrict__ offsets, const int* __restrict__ blockTotals, int n) {
  int stride = gridDim.x * blockDim.x;
  for (int i = blockIdx.x * blockDim.x + threadIdx.x; i < n; i += stride) {
    offsets[i + 1] += blockTotals[i / SCAN_VPB];
    if (i == 0) offsets[0] = 0;
  }
}

// ---------------- casts ----------------
__global__ void cast_f32_bf16(const float* __restrict__ in, ushort* __restrict__ out, int n4) {
  int i = blockIdx.x * blockDim.x + threadIdx.x;
  if (i < n4) {
    float4 v = ((const float4*)in)[i];
    ushort4 o;
    o.x = f2bf(v.x); o.y = f2bf(v.y); o.z = f2bf(v.z); o.w = f2bf(v.w);
    ((ushort4*)out)[i] = o;
  }
}

__global__ void transpose_cast(const float* __restrict__ W, ushort* __restrict__ WT,
                               int K, int N) {
  int idx = blockIdx.x * blockDim.x + threadIdx.x;
  if (idx < K * N) {
    int k = idx / N, n = idx % N;
    WT[(long)n * K + k] = f2bf(W[idx]);
  }
}

// ---------------- aggregation (bf16 in/out, fp32 accum) ----------------
__global__ __launch_bounds__(256) void aggregate128_bf16(
    const ushort* __restrict__ xb, const float* __restrict__ dis,
    const int* __restrict__ offsets, const int* __restrict__ rows_csr,
    ushort* __restrict__ outb, int N) {
  int node = blockIdx.x * 4 + (threadIdx.x >> 6);
  if (node >= N) return;
  int lane = threadIdx.x & 63;
  float di = dis[node];
  const unsigned int* xv = (const unsigned int*)xb;
  unsigned int sv = xv[(long)node * 64 + lane];
  float a0 = bf2f((ushort)sv) * di * di;
  float a1 = bf2f((ushort)(sv >> 16)) * di * di;
  int e0 = offsets[node], e1 = offsets[node + 1];
  int e = e0;
  for (; e + 3 < e1; e += 4) {
    int r0 = rows_csr[e], r1 = rows_csr[e + 1];
    int r2 = rows_csr[e + 2], r3 = rows_csr[e + 3];
    float s0 = dis[r0] * di, s1 = dis[r1] * di;
    float s2 = dis[r2] * di, s3 = dis[r3] * di;
    unsigned int v0 = xv[(long)r0 * 64 + lane];
    unsigned int v1 = xv[(long)r1 * 64 + lane];
    unsigned int v2 = xv[(long)r2 * 64 + lane];
    unsigned int v3 = xv[(long)r3 * 64 + lane];
    a0 = fmaf(bf2f((ushort)v0), s0, a0); a1 = fmaf(bf2f((ushort)(v0 >> 16)), s0, a1);
    a0 = fmaf(bf2f((ushort)v1), s1, a0); a1 = fmaf(bf2f((ushort)(v1 >> 16)), s1, a1);
    a0 = fmaf(bf2f((ushort)v2), s2, a0); a1 = fmaf(bf2f((ushort)(v2 >> 16)), s2, a1);
    a0 = fmaf(bf2f((ushort)v3), s3, a0); a1 = fmaf(bf2f((ushort)(v3 >> 16)), s3, a1);
  }
  for (; e < e1; ++e) {
    int r0 = rows_csr[e];
    float s0 = dis[r0] * di;
    unsigned int v0 = xv[(long)r0 * 64 + lane];
    a0 = fmaf(bf2f((ushort)v0), s0, a0); a1 = fmaf(bf2f((ushort)(v0 >> 16)), s0, a1);
  }
  unsigned int o = (unsigned int)f2bf(a0) | ((unsigned int)f2bf(a1) << 16);
  ((unsigned int*)outb)[(long)node * 64 + lane] = o;
}

__global__ __launch_bounds__(256) void aggregate256_bf16(
    const ushort* __restrict__ xb, const float* __restrict__ dis,
    const int* __restrict__ offsets, const int* __restrict__ rows_csr,
    ushort* __restrict__ outb, int N) {
  int node = blockIdx.x * 4 + (threadIdx.x >> 6);
  if (node >= N) return;
  int lane = threadIdx.x & 63;
  float di = dis[node];
  const uint2* xv = (const uint2*)xb;
  uint2 sv = xv[(long)node * 64 + lane];
  float a0 = bf2f((ushort)sv.x) * di * di;
  float a1 = bf2f((ushort)(sv.x >> 16)) * di * di;
  float a2 = bf2f((ushort)sv.y) * di * di;
  float a3 = bf2f((ushort)(sv.y >> 16)) * di * di;
  int e0 = offsets[node], e1 = offsets[node + 1];
  int e = e0;
  for (; e + 3 < e1; e += 4) {
    int r0 = rows_csr[e], r1 = rows_csr[e + 1];
    int r2 = rows_csr[e + 2], r3 = rows_csr[e + 3];
    float s0 = dis[r0] * di, s1 = dis[r1] * di;
    float s2 = dis[r2] * di, s3 = dis[r3] * di;
    uint2 v0 = xv[(long)r0 * 64 + lane];
    uint2 v1 = xv[(long)r1 * 64 + lane];
    uint2 v2 = xv[(long)r2 * 64 + lane];
    uint2 v3 = xv[(long)r3 * 64 + lane];
    a0 = fmaf(bf2f((ushort)v0.x), s0, a0); a1 = fmaf(bf2f((ushort)(v0.x >> 16)), s0, a1);
    a2 = fmaf(bf2f((ushort)v0.y), s0, a2); a3 = fmaf(bf2f((ushort)(v0.y >> 16)), s0, a3);
    a0 = fmaf(bf2f((ushort)v1.x), s1, a0); a1 = fmaf(bf2f((ushort)(v1.x >> 16)), s1, a1);
    a2 = fmaf(bf2f((ushort)v1.y), s1, a2); a3 = fmaf(bf2f((ushort)(v1.y >> 16)), s1, a3);
    a0 = fmaf(bf2f((ushort)v2.x), s2, a0); a1 = fmaf(bf2f((ushort)(v2.x >> 16)), s2, a1);
    a2 = fmaf(bf2f((ushort)v2.y), s2, a2); a3 = fmaf(bf2f((ushort)(v2.y >> 16)), s2, a3);
    a0 = fmaf(bf2f((ushort)v3.x), s3, a0); a1 = fmaf(bf2f((ushort)(v3.x >> 16)), s3, a1);
    a2 = fmaf(bf2f((ushort)v3.y), s3, a2); a3 = fmaf(bf2f((ushort)(v3.y >> 16)), s3, a3);
  }
  for (; e < e1; ++e) {
    int r0 = rows_csr[e];
    float s0 = dis[r0] * di;
    uint2 v0 = xv[(long)r0 * 64 + lane];
    a0 = fmaf(bf2f((ushort)v0.x), s0, a0); a1 = fmaf(bf2f((ushort)(v0.x >> 16)), s0, a1);
    a2 = fmaf(bf2f((ushort)v0.y), s0, a2); a3 = fmaf(bf2f((ushort)(v0.y >> 16)), s0, a3);
  }
  uint2 o;
  o.x = (unsigned int)f2bf(a0) | ((unsigned int)f2bf(a1) << 16);
  o.y = (unsigned int)f2bf(a2) | ((unsigned int)f2bf(a3) << 16);
  ((uint2*)outb)[(long)node * 64 + lane] = o;
}

// ---------------- MFMA GEMM ----------------
template <int K, bool OUTBF16>
__global__ __launch_bounds__(256) void gemm_mfma(
    const ushort* __restrict__ A, const ushort* __restrict__ WT,
    const float* __restrict__ bias, ushort* __restrict__ outb,
    float* __restrict__ outf, int M) {
  __shared__ ushort smem[16384];
  const int tid = threadIdx.x;
  const int lane = tid & 63;
  const int wave = tid >> 6;
  const int wm = wave >> 1, wn = wave & 1;
  const int m0 = blockIdx.x * 128;
  const int n0 = blockIdx.y * 128;

  f4_t acc[4][4] = {};

  for (int k0 = 0; k0 < K; k0 += 64) {
    __syncthreads();
    #pragma unroll
    for (int is = 0; is < 4; ++is) {
      int s = is * 256 + tid;
      int row = s >> 3;
      int ch = (s & 7) ^ (row & 7);
      long grow = m0 + row; if (grow > M - 1) grow = M - 1;
      const ushort* g = A + grow * K + k0 + ch * 8;
      gload_lds16(g, &smem[(is * 256 + wave * 64) * 8]);
    }
    #pragma unroll
    for (int is = 0; is < 4; ++is) {
      int s = is * 256 + tid;
      int row = s >> 3;
      int ch = (s & 7) ^ (row & 7);
      const ushort* g = WT + (long)(n0 + row) * K + k0 + ch * 8;
      gload_lds16(g, &smem[8192 + (is * 256 + wave * 64) * 8]);
    }
    asm volatile("s_waitcnt vmcnt(0)" ::: "memory");
    __syncthreads();
    #pragma unroll
    for (int ks = 0; ks < 2; ++ks) {
      s8_t af[4], bfr[4];
      #pragma unroll
      for (int mi = 0; mi < 4; ++mi) {
        int row = wm * 64 + mi * 16 + (lane & 15);
        int ch = (ks * 4 + (lane >> 4)) ^ (row & 7);
        af[mi] = *(const s8_t*)(&smem[row * 64 + ch * 8]);
      }
      #pragma unroll
      for (int ni = 0; ni < 4; ++ni) {
        int row = wn * 64 + ni * 16 + (lane & 15);
        int ch = (ks * 4 + (lane >> 4)) ^ (row & 7);
        bfr[ni] = *(const s8_t*)(&smem[8192 + row * 64 + ch * 8]);
      }
      #pragma unroll
      for (int mi = 0; mi < 4; ++mi)
        #pragma unroll
        for (int ni = 0; ni < 4; ++ni)
          acc[mi][ni] = mfma16(af[mi], bfr[ni], acc[mi][ni]);
    }
  }
  #pragma unroll
  for (int ni = 0; ni < 4; ++ni) {
    int col = n0 + wn * 64 + ni * 16 + (lane & 15);
    float bb = bias[col];
    #pragma unroll
    for (int mi = 0; mi < 4; ++mi) {
      #pragma unroll
      for (int r = 0; r < 4; ++r) {
        int row = m0 + wm * 64 + mi * 16 + (lane >> 4) * 4 + r;
        if (row < M) {
          float v = fmaxf(acc[mi][ni][r] + bb, 0.0f);
          if (OUTBF16) outb[(long)row * HIDC + col] = f2bf(v);
          else outf[(long)row * HIDC + col] = v;
        }
      }
    }
  }
}

// ---------------- pool via sorted-batch ranges ----------------
__global__ void find_bounds(const int* __restrict__ batch, int* __restrict__ gstart, int n) {
  int stride = gridDim.x * blockDim.x;
  for (int i = blockIdx.x * blockDim.x + threadIdx.x; i < n; i += stride) {
    int b = batch[i];
    if (i == 0) {
      for (int g = 0; g <= b; ++g) gstart[g] = 0;
    } else {
      int pb = batch[i - 1];
      if (pb != b)
        for (int g = pb + 1; g <= b; ++g) gstart[g] = i;
    }
    if (i == n - 1) {
      for (int g = b + 1; g <= NG; ++g) gstart[g] = n;
    }
  }
}

#define POOL_SPLIT 8
__global__ __launch_bounds__(HIDC) void pool_range_bf16(const ushort* __restrict__ h,
                                                        const int* __restrict__ gstart,
                                                        float* __restrict__ gsum) {
  int g = blockIdx.x;
  int s = blockIdx.y;
  int c = threadIdx.x;
  int s0 = gstart[g], s1 = gstart[g + 1];
  int len = s1 - s0;
  int chunk = (len + POOL_SPLIT - 1) / POOL_SPLIT;
  int i0 = s0 + s * chunk;
  int i1 = min(i0 + chunk, s1);
  float acc = 0.0f;
  for (int i = i0; i < i1; ++i) acc += bf2f(h[(long)i * HIDC + c]);
  if (i1 > i0) atomicAdd(&gsum[g * HIDC + c], acc);
}

// ---------------- final MLP + log_softmax ----------------
__global__ __launch_bounds__(64) void mlp_kernel(
    const float* __restrict__ gsum, const int* __restrict__ gstart,
    const float* __restrict__ Wl1, const float* __restrict__ bl1,
    const float* __restrict__ Wl2, const float* __restrict__ bl2,
    float* __restrict__ out) {
  __shared__ float g[HIDC];
  __shared__ float hid[64];
  __shared__ float logits[NCLS];
  __shared__ float red[2];
  int i = blockIdx.x;
  int t = threadIdx.x;
  int cnt = gstart[i + 1] - gstart[i];
  float inv = 1.0f / fmaxf((float)cnt, 1.0f);
  for (int c = t; c < HIDC; c += 64) g[c] = gsum[i * HIDC + c] * inv;
  __syncthreads();
  float acc = bl1[t];
  for (int c = 0; c < HIDC; ++c) acc = fmaf(g[c], Wl1[c * 64 + t], acc);
  hid[t] = fmaxf(acc, 0.0f);
  __syncthreads();
  if (t < NCLS) {
    float l = bl2[t];
    for (int c = 0; c < 64; ++c) l = fmaf(hid[c], Wl2[c * NCLS + t], l);
    logits[t] = l;
  }
  __syncthreads();
  if (t == 0) {
    float m = -1e30f;
    for (int k = 0; k < NCLS; ++k) m = fmaxf(m, logits[k]);
    float s = 0.f;
    for (int k = 0; k < NCLS; ++k) s += expf(logits[k] - m);
    red[0] = m;
    red[1] = logf(s);
  }
  __syncthreads();
  if (t < NCLS) out[i * NCLS + t] = logits[t] - red[0] - red[1];
}

extern "C" void kernel_launch(void* const* d_in, const int* in_sizes, int n_in,
                              void* d_out, int out_size, void* d_ws, size_t ws_size,
                              hipStream_t stream) {
  const float* x = (const float*)d_in[0];
  const int* edge_index = (const int*)d_in[1];
  const int* batch = (const int*)d_in[2];
  const float* W1 = (const float*)d_in[3];
  const float* b1 = (const float*)d_in[4];
  const float* W2 = (const float*)d_in[5];
  const float* b2 = (const float*)d_in[6];
  const float* Wl1 = (const float*)d_in[7];
  const float* bl1 = (const float*)d_in[8];
  const float* Wl2 = (const float*)d_in[9];
  const float* bl2 = (const float*)d_in[10];
  float* out = (float*)d_out;

  const int N = in_sizes[0] / INC;     // 50000
  const int E = in_sizes[1] / 2;       // 1600000
  const int* erow = edge_index;
  const int* ecol = edge_index + E;

  char* p = (char*)d_ws;
  auto alloc = [&](size_t bytes) {
    void* r = (void*)p;
    p += (bytes + 255) & ~(size_t)255;
    return r;
  };
  int* deg = (int*)alloc((size_t)N * 4);
  float* dis = (float*)alloc((size_t)N * 4);
  int* offsets = (int*)alloc((size_t)(N + 1) * 4);
  int* rows_csr = (int*)alloc((size_t)E * 4);
  uint2* part = (uint2*)alloc((size_t)E * 8);
  int* hist = (int*)alloc((size_t)(NB * NBLK) * 4);
  int* histBase = (int*)alloc((size_t)(NB * NBLK + 1) * 4);
  float* gsum = (float*)alloc((size_t)NG * HIDC * 4);
  int* gstart = (int*)alloc((size_t)(NG + 1) * 4);
  int* blockTotals = (int*)alloc((size_t)256 * 4);
  ushort* W1T = (ushort*)alloc((size_t)INC * HIDC * 2);
  ushort* W2T = (ushort*)alloc((size_t)HIDC * HIDC * 2);
  ushort* xb = (ushort*)alloc((size_t)N * INC * 2);
  ushort* agg1b = (ushort*)alloc((size_t)N * INC * 2);
  ushort* h1b = (ushort*)alloc((size_t)N * HIDC * 2);
  ushort* agg2b = (ushort*)alloc((size_t)N * HIDC * 2);
  ushort* h2b = xb;  // reuse (xb+agg1b dead after GEMM1)

  hipMemsetAsync(gsum, 0, (size_t)NG * HIDC * 4, stream);

  // bucketed CSR build
  const int chunk = (E + NBLK - 1) / NBLK;
  edge_hist<<<NBLK, 256, 0, stream>>>(ecol, hist, E, chunk);
  {
    const int nh = NB * NBLK;
    const int nbh = (nh + SCAN_VPB - 1) / SCAN_VPB;
    scanA<<<nbh, SCAN_T, 0, stream>>>(hist, histBase, blockTotals, nh);
    scanB<<<1, 64, 0, stream>>>(blockTotals, nbh);
    scanC<<<(nh + 255) / 256, 256, 0, stream>>>(histBase, blockTotals, nh);
  }
  edge_partition<<<NBLK, 256, 0, stream>>>(erow, ecol, histBase, part, E, chunk);
  bucket_deg<<<NB, 256, 0, stream>>>(part, histBase, deg, N);
  compute_dis<<<(N + 255) / 256, 256, 0, stream>>>(deg, dis, N);
  {
    const int nb = (N + SCAN_VPB - 1) / SCAN_VPB;
    scanA<<<nb, SCAN_T, 0, stream>>>(deg, offsets, blockTotals, N);
    scanB<<<1, 64, 0, stream>>>(blockTotals, nb);
    scanC<<<(N + 255) / 256, 256, 0, stream>>>(offsets, blockTotals, N);
  }
  bucket_csr<<<NB, 256, 0, stream>>>(part, histBase, offsets, rows_csr, N);

  // casts
  cast_f32_bf16<<<(N * INC / 4 + 255) / 256, 256, 0, stream>>>(x, xb, N * INC / 4);
  transpose_cast<<<(INC * HIDC + 255) / 256, 256, 0, stream>>>(W1, W1T, INC, HIDC);
  transpose_cast<<<(HIDC * HIDC + 255) / 256, 256, 0, stream>>>(W2, W2T, HIDC, HIDC);

  // layer 1
  aggregate128_bf16<<<(N + 3) / 4, 256, 0, stream>>>(xb, dis, offsets, rows_csr, agg1b, N);
  {
    dim3 grid((N + 127) / 128, HIDC / 128);
    gemm_mfma<INC, true><<<grid, 256, 0, stream>>>(agg1b, W1T, b1, h1b, nullptr, N);
  }
  // layer 2
  aggregate256_bf16<<<(N + 3) / 4, 256, 0, stream>>>(h1b, dis, offsets, rows_csr, agg2b, N);
  {
    dim3 grid((N + 127) / 128, HIDC / 128);
    gemm_mfma<HIDC, true><<<grid, 256, 0, stream>>>(agg2b, W2T, b2, h2b, nullptr, N);
  }
  // pool + MLP
  find_bounds<<<(N + 255) / 256, 256, 0, stream>>>(batch, gstart, N);
  {
    dim3 pgrid(NG, POOL_SPLIT);
    pool_range_bf16<<<pgrid, HIDC, 0, stream>>>(h2b, gstart, gsum);
  }
  mlp_kernel<<<NG, 64, 0, stream>>>(gsum, gstart, Wl1, bl1, Wl2, bl2, out);
}